// Round 1
// baseline (127.983 us; speedup 1.0000x reference)
//
#include <hip/hip_runtime.h>

#define VOCAB 50257

typedef __attribute__((ext_vector_type(4))) float floatx4;
typedef __attribute__((ext_vector_type(4))) int intx4;
typedef __attribute__((ext_vector_type(8))) int int8v;

// identity E8M0 scales (2^0) in every byte -> opsel-proof
#define SC1 0x7F7F7F7F
#define MFMA_F4F8(a, b, c) \
  __builtin_amdgcn_mfma_scale_f32_16x16x128_f8f6f4((a), (b), (c), 4, 0, 0, SC1, 0, SC1)

// Barrier with lgkm-only drain: makes this wave's LDS writes visible before the
// barrier, but lets global-memory prefetches (W frags for the next phase/domain)
// stay in flight across it. __syncthreads() would drain vmcnt(0) and stall every
// wave on its weight prefetch at every one of the 32 barriers.
#define BARRIER()                                      \
  do {                                                 \
    asm volatile("s_waitcnt lgkmcnt(0)" ::: "memory"); \
    __builtin_amdgcn_s_barrier();                      \
    asm volatile("" ::: "memory");                     \
  } while (0)

// ---------------------------------------------------------------------------
// fp4 e2m1 quantizer (software RNE-ish to grid {0,.5,1,1.5,2,3,4,6}), x256.
// ---------------------------------------------------------------------------
static __device__ __forceinline__ unsigned fp4q(float v) {
  float a = fabsf(v) * 256.f;
  unsigned s = (v < 0.f) ? 8u : 0u;
  unsigned c;
  if (a < 0.25f) c = 0;
  else if (a < 0.75f) c = 1;
  else if (a < 1.25f) c = 2;
  else if (a < 1.75f) c = 3;
  else if (a < 2.5f)  c = 4;
  else if (a < 3.5f)  c = 5;
  else if (a < 5.0f)  c = 6;
  else c = 7;
  return s | c;
}

// ---------------------------------------------------------------------------
// Weight pre-shuffle: fp32 -> fp4 (x256), frag-major for K=128 scaled MFMA.
// A-frag assumption: A[m = lane&15][k = 32*(lane>>4) + 8*r + j], r=dword 0..3,
// j = nibble 0..7 (element j at bits 4j). One b128/lane per 16x128 tile.
// W1f dword idx (per domain, 4096 dw): ((p*64+lane)*4 + r), p = 4w+mt:
//   -> W1[d][16p + (l&15)][32*(l>>4) + 8r + j]
// W2f: p = (2w+et)*2 + kh -> W2[d][16*(p>>1) + (l&15)][128*(p&1) + 32*(l>>4) + 8r + j]
// ---------------------------------------------------------------------------
__global__ void prep_weights(const float* __restrict__ W1, const float* __restrict__ W2,
                             unsigned* __restrict__ W1f, unsigned* __restrict__ W2f) {
  int g = blockIdx.x * 256 + threadIdx.x;   // 0..131071
  int arr = g >> 16;
  int s = g & 65535;
  int d = s >> 12;
  int gg = s & 4095;         // dword within domain
  int p = gg >> 8;           // 0..15
  int lane = (gg >> 2) & 63;
  int r = gg & 3;
  int lm = lane & 15, lq = lane >> 4;
  const float* src;
  unsigned* dst;
  if (arr == 0) {
    src = W1 + (size_t)(d * 256 + 16 * p + lm) * 128 + 32 * lq + 8 * r;
    dst = W1f + (size_t)d * 4096 + gg;
  } else {
    src = W2 + (size_t)(d * 128 + 16 * (p >> 1) + lm) * 256 + 128 * (p & 1) + 32 * lq + 8 * r;
    dst = W2f + (size_t)d * 4096 + gg;
  }
  unsigned pk = 0;
#pragma unroll
  for (int j = 0; j < 8; ++j) pk |= fp4q(src[j]) << (4 * j);
  *dst = pk;
}

static __device__ __forceinline__ int pack_fp8(float a, float b, float c, float d) {
  int v = __builtin_amdgcn_cvt_pk_fp8_f32(a, b, 0, false);
  return __builtin_amdgcn_cvt_pk_fp8_f32(c, d, v, true);
}

// ---------------------------------------------------------------------------
// Block = 4 waves, 32 tokens; grid 1024 -> 4 blocks/CU.
// GEMM1 m-split (wave w -> mid[64w..64w+64)); GEMM2 e-split (h[32w..32w+32)).
// K=128 scaled MFMA, A = fp4 weights (x256, identity scales), B = fp8 act.
// h master fp32 x131072 in regs; GEMM2 accumulates directly into it.
// h fp8 = x8 (hm*2^-14); mid fp8 = mask*512*0.1*gelu = acc*(k0+k1*acc),
//   k0 = 0.0125, k1 = 4.87035e-6 (acc = 2048*x).
// LDS: mid [0,8K) rows 256B, h [8K,12K) rows 128B; fp32 stag at init (16K).
// XOR-16B-unit swizzle keyed by row&7 (= lm&7 for reader AND writer).
// This round: lgkm-only barriers (W prefetches fly across), W2 prefetched a
// full phase earlier, B-frags built by direct tuple loads, per-mt mid pack.
// ---------------------------------------------------------------------------
__launch_bounds__(256, 4)
__global__ void domain_chain(const int* __restrict__ x,
                             const float* __restrict__ base_embed,
                             const int* __restrict__ membership,
                             const unsigned char* __restrict__ W1f,
                             const unsigned char* __restrict__ W2f,
                             float* __restrict__ out) {
  __shared__ __align__(16) unsigned char act[16384];
  __shared__ int xs[32];
  __shared__ int mws[32];

  const int tid = threadIdx.x;       // 0..255
  const int w = tid >> 6;            // wave 0..3
  const int lane = tid & 63;
  const int lm = lane & 15, lq = lane >> 4;
  const int key = lm & 7;
  const int tokbase = blockIdx.x * 32;

  if (tid < 32) xs[tid] = x[tokbase + tid];
  __syncthreads();
  if (tid >= 32 && tid < 64) {
    int t = tid - 32;
    int tok = xs[t];
    int mw = 0;
#pragma unroll
    for (int d = 0; d < 16; ++d)
      mw |= (membership[d * VOCAB + tok] != 0 ? 1 : 0) << d;
    mws[t] = mw;
  }
  // stage h0 fp32 (32 tok x 128 f32 = 16 KB), float4 units swizzled ^(t&7)
  float4* stag4 = (float4*)act;
#pragma unroll
  for (int i = 0; i < 4; ++i) {
    int idx = tid + i * 256;         // 0..1023
    int t = idx >> 5, c4 = idx & 31;
    stag4[t * 32 + (c4 ^ (t & 7))] = ((const float4*)base_embed)[(size_t)xs[t] * 32 + c4];
  }
  __syncthreads();

  // h master fp32 x131072 (e-slice, MFMA C-layout): hm[et][nt] reg r =
  //   131072 * h[e = 32w+16et+4lq+r][tok = 16nt+lm]
  floatx4 hm[2][2];
  int mwr[2];
#pragma unroll
  for (int nt = 0; nt < 2; ++nt) mwr[nt] = mws[nt * 16 + lm];
#pragma unroll
  for (int et = 0; et < 2; ++et)
#pragma unroll
    for (int nt = 0; nt < 2; ++nt) {
      float4 v = stag4[(nt * 16 + lm) * 32 + ((8 * w + 4 * et + lq) ^ key)];
      hm[et][nt] = (floatx4){v.x * 131072.f, v.y * 131072.f, v.z * 131072.f, v.w * 131072.f};
    }

  // domain-invariant LDS byte offsets (unit16 XOR-swizzled by key)
  // h rows at 8192 + row*128 (8 units); mid rows at row*256 (16 units)
  // read addr = {m,h}row[nt] + sw[u] (+128*kh for mid high half, const-folded)
  int mrow[2], hrow[2], sw[2], mwu[4], hwu[2];
#pragma unroll
  for (int nt = 0; nt < 2; ++nt) {
    mrow[nt] = (nt * 16 + lm) * 256;
    hrow[nt] = 8192 + (nt * 16 + lm) * 128;
  }
#pragma unroll
  for (int u = 0; u < 2; ++u) sw[u] = ((2 * lq + u) ^ key) << 4;
#pragma unroll
  for (int mt = 0; mt < 4; ++mt) mwu[mt] = (((4 * w + mt) ^ key) << 4) + 4 * lq;
#pragma unroll
  for (int et = 0; et < 2; ++et) hwu[et] = (((2 * w + et) ^ key) << 4) + 4 * lq;

  __syncthreads();   // stag reads done; act reused as mid/h

  // publish initial h fp8 (x8 = hm * 2^-14)
#pragma unroll
  for (int et = 0; et < 2; ++et)
#pragma unroll
    for (int nt = 0; nt < 2; ++nt)
      *(int*)(act + hrow[nt] + hwu[et]) =
          pack_fp8(hm[et][nt][0] * 6.1035156e-5f, hm[et][nt][1] * 6.1035156e-5f,
                   hm[et][nt][2] * 6.1035156e-5f, hm[et][nt][3] * 6.1035156e-5f);
  __syncthreads();

  const floatx4 vz = {0.f, 0.f, 0.f, 0.f};
  const intx4 z4 = 0;
  const size_t laneoff = (size_t)lane * 16;

  // persistent GEMM1 A-operand tuples: tops zeroed once (fp4 -> HW reads low
  // 4 dwords; zero tops kept loop-invariant), prefetch writes low halves only.
  int8v aw8[4];
#pragma unroll
  for (int mt = 0; mt < 4; ++mt) aw8[mt] = (int8v){0, 0, 0, 0, 0, 0, 0, 0};
  {
    const unsigned char* w1d = W1f + (size_t)(w * 4) * 1024 + laneoff;
#pragma unroll
    for (int mt = 0; mt < 4; ++mt)
      *(intx4*)&aw8[mt] = *(const intx4*)(w1d + mt * 1024);
  }
  // W2 frags for d=0, prefetched before the loop (persist across iterations)
  intx4 bw[2][2];
  {
    const unsigned char* w2d = W2f + (size_t)(w * 4) * 1024 + laneoff;
#pragma unroll
    for (int et = 0; et < 2; ++et)
#pragma unroll
      for (int kh = 0; kh < 2; ++kh)
        bw[et][kh] = *(const intx4*)(w2d + (et * 2 + kh) * 1024);
  }

#pragma unroll 1
  for (int d = 0; d < 16; ++d) {
    // ---- phase A: GEMM1 (m=64 slice, n=32 tokens, K=128 in ONE mfma)
    // h B-frags first (critical path), built by direct tuple loads
    int8v hb[2];
#pragma unroll
    for (int nt = 0; nt < 2; ++nt) {
      ((intx4*)&hb[nt])[0] = *(const intx4*)(act + hrow[nt] + sw[0]);
      ((intx4*)&hb[nt])[1] = *(const intx4*)(act + hrow[nt] + sw[1]);
    }
    float k0[2], k1[2];
#pragma unroll
    for (int nt = 0; nt < 2; ++nt) {
      float on = ((mwr[nt] >> d) & 1) ? 1.f : 0.f;
      k0[nt] = 0.0125f * on;
      k1[nt] = 4.87035e-6f * on;
    }
    // mid_stored = mask * acc*(k0 + k1*acc)   [= 512*0.1*gelu(acc/2048)]
    // pack per-mt to keep accumulator liveness at 8 regs
#pragma unroll
    for (int mt = 0; mt < 4; ++mt) {
      floatx4 a0 = MFMA_F4F8(aw8[mt], hb[0], vz);
      floatx4 a1 = MFMA_F4F8(aw8[mt], hb[1], vz);
      *(int*)(act + mrow[0] + mwu[mt]) =
          pack_fp8(a0[0] * (k0[0] + k1[0] * a0[0]), a0[1] * (k0[0] + k1[0] * a0[1]),
                   a0[2] * (k0[0] + k1[0] * a0[2]), a0[3] * (k0[0] + k1[0] * a0[3]));
      *(int*)(act + mrow[1] + mwu[mt]) =
          pack_fp8(a1[0] * (k0[1] + k1[1] * a1[0]), a1[1] * (k0[1] + k1[1] * a1[1]),
                   a1[2] * (k0[1] + k1[1] * a1[2]), a1[3] * (k0[1] + k1[1] * a1[3]));
    }
    BARRIER();   // mid visible; all phase-A h reads drained by lgkmcnt(0)

    // ---- phase B: GEMM2 (m=32 e-slice, n=32 tokens, K=256 = 2 mfma)
    // mid B-frags first (critical path)
    int8v mb[2][2];
#pragma unroll
    for (int nt = 0; nt < 2; ++nt)
#pragma unroll
      for (int kh = 0; kh < 2; ++kh) {
        ((intx4*)&mb[nt][kh])[0] = *(const intx4*)(act + mrow[nt] + 128 * kh + sw[0]);
        ((intx4*)&mb[nt][kh])[1] = *(const intx4*)(act + mrow[nt] + 128 * kh + sw[1]);
      }
#pragma unroll
    for (int et = 0; et < 2; ++et)
#pragma unroll
      for (int kh = 0; kh < 2; ++kh) {
        int8v a = __builtin_shufflevector(bw[et][kh], z4, 0, 1, 2, 3, 4, 5, 6, 7);
#pragma unroll
        for (int nt = 0; nt < 2; ++nt)
          hm[et][nt] = MFMA_F4F8(a, mb[nt][kh], hm[et][nt]);
      }
    // prefetch NEXT domain's W1 and W2 (aw8/bw dead); these loads stay in
    // flight across BARRIER and land during next phase A.
    {
      const unsigned char* w1n = W1f + ((size_t)(d + 1) << 14) + (size_t)(w * 4) * 1024 + laneoff;
#pragma unroll
      for (int mt = 0; mt < 4; ++mt)
        *(intx4*)&aw8[mt] = *(const intx4*)(w1n + mt * 1024);
      // (d=15: W1 prefetch overreads into W2f: benign. W2 wraps via &15.)
      const unsigned char* w2n = W2f + ((size_t)((d + 1) & 15) << 14) + (size_t)(w * 4) * 1024 + laneoff;
#pragma unroll
      for (int et = 0; et < 2; ++et)
#pragma unroll
        for (int kh = 0; kh < 2; ++kh)
          bw[et][kh] = *(const intx4*)(w2n + (et * 2 + kh) * 1024);
    }
    // republish h fp8 (x8 = hm * 2^-14)
#pragma unroll
    for (int et = 0; et < 2; ++et)
#pragma unroll
      for (int nt = 0; nt < 2; ++nt)
        *(int*)(act + hrow[nt] + hwu[et]) =
            pack_fp8(hm[et][nt][0] * 6.1035156e-5f, hm[et][nt][1] * 6.1035156e-5f,
                     hm[et][nt][2] * 6.1035156e-5f, hm[et][nt][3] * 6.1035156e-5f);
    BARRIER();
  }

  // ---- epilogue: out[token][e] fp32 = hm / 131072, 16B stores
  const float inv = 1.0f / 131072.0f;
#pragma unroll
  for (int et = 0; et < 2; ++et)
#pragma unroll
    for (int nt = 0; nt < 2; ++nt) {
      floatx4 v = hm[et][nt] * inv;
      *(floatx4*)&out[(size_t)(tokbase + nt * 16 + lm) * 128 + 32 * w + 16 * et + 4 * lq] = v;
    }
}

extern "C" void kernel_launch(void* const* d_in, const int* in_sizes, int n_in,
                              void* d_out, int out_size, void* d_ws, size_t ws_size,
                              hipStream_t stream) {
  const int* x = (const int*)d_in[0];
  const float* base_embed = (const float*)d_in[1];
  const float* W1 = (const float*)d_in[2];
  const float* W2 = (const float*)d_in[3];
  const int* membership = (const int*)d_in[4];
  float* out = (float*)d_out;

  unsigned* W1f = (unsigned*)d_ws;                 // 16 dom x 16KB = 256KB fp4
  unsigned* W2f = W1f + 16 * 4096;                 // 256KB (d=15 W1 prefetch
                                                   // overreads into this: benign)

  prep_weights<<<512, 256, 0, stream>>>(W1, W2, W1f, W2f);

  const int n_tokens = in_sizes[0];                // 32768
  domain_chain<<<n_tokens / 32, 256, 0, stream>>>(
      x, base_embed, membership, (const unsigned char*)W1f, (const unsigned char*)W2f, out);
}